// Round 8
// baseline (90.344 us; speedup 1.0000x reference)
//
#include <hip/hip_runtime.h>
#include <hip/hip_bf16.h>

#define BATCH 4
#define NPTS 8192
#define TPB 256
#define RSPLIT 8                    // row-split partial-min slices (no atomics)
#define CGROUPS 16                  // colgroups per side (512 cols each)
#define TOTAL (2 * BATCH * NPTS)    // 65536 output slots
#define GRID (8 * CGROUPS * RSPLIT) // 1024 blocks, 4/CU

typedef short bf16x8 __attribute__((ext_vector_type(8)));
typedef float f32x16 __attribute__((ext_vector_type(16)));

__device__ __forceinline__ unsigned short b16(float f) {   // fp32 -> bf16 RNE (HW cvt)
  __hip_bfloat16 h = __float2bfloat16(f);
  return __builtin_bit_cast(unsigned short, h);
}
__device__ __forceinline__ float b2f(unsigned short h) {
  return __uint_as_float(((unsigned)h) << 16);
}

// K=16 packed rows (R8/R10/R11-verified exact, absmax 0.0):
//  roleA(x): [(-2x)h(3), (-2x)l(3), (-2x)h(3), x2h, x2l, 1,   1,  0,0,0]
//  roleB(y): [yh(3),     yh(3),     yl(3),     1,   1, y2h, y2l, 0,0,0]
// roleA.roleB = squared distance minus (-2x)l.yl (~1e-5 << 9.3e-4 threshold).
__device__ __forceinline__ void pack_halves(uint4* lo, uint4* hi, float cx,
                                            float cy, float cz, bool roleA) {
  float n2 = cx * cx + cy * cy + cz * cz;
  float vx = roleA ? -2.f * cx : cx;
  float vy = roleA ? -2.f * cy : cy;
  float vz = roleA ? -2.f * cz : cz;
  unsigned hx = b16(vx), hy = b16(vy), hz = b16(vz);
  unsigned lx = b16(vx - b2f(hx)), ly = b16(vy - b2f(hy)), lz = b16(vz - b2f(hz));
  unsigned nh = b16(n2), nl = b16(n2 - b2f(nh));
  const unsigned ONE = 0x3F80u;
  if (roleA) {
    *lo = make_uint4(hx | (hy << 16), hz | (lx << 16), ly | (lz << 16), hx | (hy << 16));
    *hi = make_uint4(hz | (nh << 16), nl | (ONE << 16), ONE, 0u);
  } else {
    *lo = make_uint4(hx | (hy << 16), hz | (hx << 16), hy | (hz << 16), lx | (ly << 16));
    *hi = make_uint4(lz | (ONE << 16), ONE | (nh << 16), nl, 0u);
  }
}

// R19 — ABLATION ROUND. V0 = R15 verbatim (best known, real result path).
// V1 = NOMIN: MFMA executed (kept live), min-tree removed (d read 2x not 16x)
//      -> isolates the cost of consuming the MFMA accumulator with VALU
//      (suspected v_accvgpr_read tax: acc likely in AGPRs, 16 reads/MFMA).
// V3 = PACK-ONLY: staging + packs + barrier, no tile loop -> floor.
// V1/V3 write garbage mins to scratch slices; reduce reads only V0's slice.
template <int V>
__global__ __launch_bounds__(TPB, 4) void chamfer_nn(
    const float* __restrict__ pred, const float* __restrict__ gt,
    float* __restrict__ partial, float* __restrict__ out) {
  __shared__ __align__(16) unsigned short sB[1024 * 16];   // 32 KB row frags

  int blk = blockIdx.x;
  int rq   = blk & (RSPLIT - 1);         // row slice (1024 rows = 32 tiles)
  int cg   = (blk >> 3) & (CGROUPS - 1); // colgroup (512 cols = 16 tiles)
  int side = blk >> 7;                   // dir*4 + b
  int dir = side >> 2, b = side & 3;

  const float* As = (dir ? gt : pred) + (size_t)b * NPTS * 3;  // cols (outputs)
  const float* Bs = (dir ? pred : gt) + (size_t)b * NPTS * 3;  // rows (min'ed)

  int t = threadIdx.x, w = t >> 6, lane = t & 63;
  if constexpr (V == 0)
    if (blk == 0 && t == 0) out[0] = 0.f;  // zero accumulator for reduce pass

  int rowbase = rq * 1024;

  // ---- Stage rows: 4 points/thread into lane-ordered LDS units. ----
  #pragma unroll
  for (int h = 0; h < 4; ++h) {
    int p = h * 256 + t;                 // local row 0..1023
    int gp = rowbase + p;
    uint4 lo, hi;
    pack_halves(&lo, &hi, Bs[gp * 3], Bs[gp * 3 + 1], Bs[gp * 3 + 2], true);
    unsigned short* u0 = sB + ((p >> 5) * 64 + (p & 31)) * 8;
    *(uint4*)u0 = lo;
    *(uint4*)(u0 + 32 * 8) = hi;
  }

  // ---- Col operands in-register: wave w owns col tiles cg*16+w*4+{0..3}.
  bf16x8 af[4];
  #pragma unroll
  for (int j = 0; j < 4; ++j) {
    int gp = (cg * 16 + w * 4 + j) * 32 + (lane & 31);
    uint4 lo, hi;
    pack_halves(&lo, &hi, As[gp * 3], As[gp * 3 + 1], As[gp * 3 + 2], false);
    uint4 sel = (lane < 32) ? lo : hi;
    af[j] = __builtin_bit_cast(bf16x8, sel);
  }

  __syncthreads();   // single barrier: rows staged

  const f32x16 Z = {0.f,0.f,0.f,0.f,0.f,0.f,0.f,0.f,0.f,0.f,0.f,0.f,0.f,0.f,0.f,0.f};
  float m[4] = {3.4e38f, 3.4e38f, 3.4e38f, 3.4e38f};

  if constexpr (V == 3) {
    // PACK-ONLY: keep staging + col packs live; one token LDS read.
    m[0] = fminf(m[0], b2f(sB[t * 8]));
    #pragma unroll
    for (int j = 0; j < 4; ++j) {
      uint4 k = __builtin_bit_cast(uint4, af[j]);
      asm volatile("" :: "v"(k.x), "v"(k.y), "v"(k.z), "v"(k.w));
    }
  } else {
    #pragma unroll 2
    for (int rt = 0; rt < 32; ++rt) {
      bf16x8 bf = *(const bf16x8*)(sB + (rt * 64 + lane) * 8);
      #pragma unroll
      for (int j = 0; j < 4; ++j) {
        f32x16 d = __builtin_amdgcn_mfma_f32_32x32x16_bf16(bf, af[j], Z, 0, 0, 0);
        if constexpr (V == 1) {
          m[j] = fminf(m[j], d[0]);        // 1 acc read
          asm volatile("" :: "v"(d[12]));  // keep MFMA alive (rule #17)
        } else {
          float t0 = fminf(fminf(d[0], d[1]), d[2]);
          float t1 = fminf(fminf(d[3], d[4]), d[5]);
          float t2 = fminf(fminf(d[6], d[7]), d[8]);
          float t3 = fminf(fminf(d[9], d[10]), d[11]);
          float t4 = fminf(fminf(d[12], d[13]), d[14]);
          float u0 = fminf(fminf(t0, t1), d[15]);
          float u1 = fminf(fminf(t2, t3), t4);
          m[j] = fminf(fminf(m[j], u0), u1);
        }
      }
    }
  }

  #pragma unroll
  for (int j = 0; j < 4; ++j)
    m[j] = fminf(m[j], __shfl_xor(m[j], 32, 64));  // merge row halves
  if (lane < 32) {
    float* dst = partial + (size_t)rq * TOTAL + (size_t)side * NPTS;
    #pragma unroll
    for (int j = 0; j < 4; ++j)
      dst[(cg * 16 + w * 4 + j) * 32 + lane] = fmaxf(m[j], 0.f);
  }
}

// Reduce: min over RSPLIT partials per slot, block-sum, one atomicAdd/block.
__global__ __launch_bounds__(TPB) void chamfer_reduce(
    const float* __restrict__ partial, float* __restrict__ out) {
  int t = threadIdx.x;
  int s = blockIdx.x * TPB + t;       // slot 0..65535
  float v = partial[s];
  #pragma unroll
  for (int r = 1; r < RSPLIT; ++r)
    v = fminf(v, partial[(size_t)r * TOTAL + s]);
  #pragma unroll
  for (int off = 32; off > 0; off >>= 1) v += __shfl_down(v, off, 64);
  __shared__ float wsum[4];
  int wave = t >> 6, lane = t & 63;
  if (lane == 0) wsum[wave] = v;
  __syncthreads();
  if (t == 0) {
    float tot = (wsum[0] + wsum[1]) + (wsum[2] + wsum[3]);
    atomicAdd(out, tot * (1.f / (float)(BATCH * NPTS)));
  }
}

extern "C" void kernel_launch(void* const* d_in, const int* in_sizes, int n_in,
                              void* d_out, int out_size, void* d_ws, size_t ws_size,
                              hipStream_t stream) {
  const float* pred = (const float*)d_in[0];
  const float* gt   = (const float*)d_in[1];
  float* out        = (float*)d_out;
  float* partial    = (float*)d_ws;   // RSPLIT x 65536 floats = 2 MB (real)
  const size_t SLICE = (size_t)RSPLIT * TOTAL;    // floats per slice
  float* scr1 = partial + SLICE;      // V1 scratch (2 MB)
  float* scr3 = partial + 2 * SLICE;  // V3 scratch (2 MB)

  chamfer_nn<0><<<dim3(GRID), dim3(TPB), 0, stream>>>(pred, gt, partial, out);
  chamfer_reduce<<<dim3(TOTAL / TPB), dim3(TPB), 0, stream>>>(partial, out);
  // --- ablation probes (write scratch; do not affect the result) ---
  chamfer_nn<1><<<dim3(GRID), dim3(TPB), 0, stream>>>(pred, gt, scr1, out);
  chamfer_nn<3><<<dim3(GRID), dim3(TPB), 0, stream>>>(pred, gt, scr3, out);
}

// Round 9
// 77.962 us; speedup vs baseline: 1.1588x; 1.1588x over previous
//
#include <hip/hip_runtime.h>
#include <hip/hip_bf16.h>

#define BATCH 4
#define NPTS 8192
#define TPB 256
#define RSPLIT 8                    // row-split partial-min slices (no atomics)
#define CGROUPS 16                  // colgroups per side (512 cols each)
#define TOTAL (2 * BATCH * NPTS)    // 65536 output slots
#define GRID (8 * CGROUPS * RSPLIT) // 1024 blocks, 4/CU

typedef short bf16x8 __attribute__((ext_vector_type(8)));
typedef float f32x16 __attribute__((ext_vector_type(16)));

__device__ __forceinline__ unsigned short b16(float f) {   // fp32 -> bf16 RNE (HW cvt)
  __hip_bfloat16 h = __float2bfloat16(f);
  return __builtin_bit_cast(unsigned short, h);
}
__device__ __forceinline__ float b2f(unsigned short h) {
  return __uint_as_float(((unsigned)h) << 16);
}

// K=16 packed rows (R8/R10/R11-verified exact, absmax 0.0):
//  roleA(x): [(-2x)h(3), (-2x)l(3), (-2x)h(3), x2h, x2l, 1,   1,  0,0,0]
//  roleB(y): [yh(3),     yh(3),     yl(3),     1,   1, y2h, y2l, 0,0,0]
// roleA.roleB = squared distance minus (-2x)l.yl (~1e-5 << 9.3e-4 threshold).
__device__ __forceinline__ void pack_halves(uint4* lo, uint4* hi, float cx,
                                            float cy, float cz, bool roleA) {
  float n2 = cx * cx + cy * cy + cz * cz;
  float vx = roleA ? -2.f * cx : cx;
  float vy = roleA ? -2.f * cy : cy;
  float vz = roleA ? -2.f * cz : cz;
  unsigned hx = b16(vx), hy = b16(vy), hz = b16(vz);
  unsigned lx = b16(vx - b2f(hx)), ly = b16(vy - b2f(hy)), lz = b16(vz - b2f(hz));
  unsigned nh = b16(n2), nl = b16(n2 - b2f(nh));
  const unsigned ONE = 0x3F80u;
  if (roleA) {
    *lo = make_uint4(hx | (hy << 16), hz | (lx << 16), ly | (lz << 16), hx | (hy << 16));
    *hi = make_uint4(hz | (nh << 16), nl | (ONE << 16), ONE, 0u);
  } else {
    *lo = make_uint4(hx | (hy << 16), hz | (hx << 16), hy | (hz << 16), lx | (ly << 16));
    *hi = make_uint4(lz | (ONE << 16), ONE | (nh << 16), nl, 0u);
  }
}

// R20 — R15's structure + software-pipelined consumption.
// R19 ablation: V0~28us, V1(NOMIN)~11us => consuming the 16 acc elements
// per MFMA is ~15us, ~5x its VALU issue cost. Diagnosis: ONE live d tuple
// serializes (MFMA -> hazard gap -> 16-elem tree -> next MFMA). Fix: two
// named d buffers (dA/dB) so every min-tree runs while two MFMAs are in
// flight, + 1-iter ds_read prefetch (bf/bfn) to hide ~120cyc LDS latency.
// Consumption order per d unchanged -> bit-identical mins (absmax 0.0).
// Regs ~80 < 128 cap (4 waves/EU). Everything else R15-verified: lane-
// ordered LDS units ((p>>5)*64+(p&31), hi +32, writer/reader lane-stride-1,
// 0 conflicts measured), in-register col pack (lane<32 lo else hi), in-lane
// row-min (C/D: col=lane&31, row=(reg&3)+8*(reg>>2)+4*(lane>>5)),
// shfl_xor(32) merge, coalesced partial stores, separate reduce kernel.
__global__ __launch_bounds__(TPB, 4) void chamfer_nn(
    const float* __restrict__ pred, const float* __restrict__ gt,
    float* __restrict__ partial, float* __restrict__ out) {
  __shared__ __align__(16) unsigned short sB[1024 * 16];   // 32 KB row frags

  int blk = blockIdx.x;
  int rq   = blk & (RSPLIT - 1);         // row slice (1024 rows = 32 tiles)
  int cg   = (blk >> 3) & (CGROUPS - 1); // colgroup (512 cols = 16 tiles)
  int side = blk >> 7;                   // dir*4 + b
  int dir = side >> 2, b = side & 3;

  const float* As = (dir ? gt : pred) + (size_t)b * NPTS * 3;  // cols (outputs)
  const float* Bs = (dir ? pred : gt) + (size_t)b * NPTS * 3;  // rows (min'ed)

  int t = threadIdx.x, w = t >> 6, lane = t & 63;
  if (blk == 0 && t == 0) out[0] = 0.f;   // zero accumulator for reduce pass

  int rowbase = rq * 1024;

  // ---- Stage rows: 4 points/thread into lane-ordered LDS units. ----
  #pragma unroll
  for (int h = 0; h < 4; ++h) {
    int p = h * 256 + t;                 // local row 0..1023
    int gp = rowbase + p;
    uint4 lo, hi;
    pack_halves(&lo, &hi, Bs[gp * 3], Bs[gp * 3 + 1], Bs[gp * 3 + 2], true);
    unsigned short* u0 = sB + ((p >> 5) * 64 + (p & 31)) * 8;
    *(uint4*)u0 = lo;
    *(uint4*)(u0 + 32 * 8) = hi;
  }

  // ---- Col operands in-register: wave w owns col tiles cg*16+w*4+{0..3}.
  bf16x8 af0, af1, af2, af3;
  {
    uint4 lo, hi;
    int gp = (cg * 16 + w * 4) * 32 + (lane & 31);
    pack_halves(&lo, &hi, As[gp * 3], As[gp * 3 + 1], As[gp * 3 + 2], false);
    af0 = __builtin_bit_cast(bf16x8, (lane < 32) ? lo : hi);
    gp += 32;
    pack_halves(&lo, &hi, As[gp * 3], As[gp * 3 + 1], As[gp * 3 + 2], false);
    af1 = __builtin_bit_cast(bf16x8, (lane < 32) ? lo : hi);
    gp += 32;
    pack_halves(&lo, &hi, As[gp * 3], As[gp * 3 + 1], As[gp * 3 + 2], false);
    af2 = __builtin_bit_cast(bf16x8, (lane < 32) ? lo : hi);
    gp += 32;
    pack_halves(&lo, &hi, As[gp * 3], As[gp * 3 + 1], As[gp * 3 + 2], false);
    af3 = __builtin_bit_cast(bf16x8, (lane < 32) ? lo : hi);
  }

  __syncthreads();   // single barrier: rows staged

  const f32x16 Z = {0.f,0.f,0.f,0.f,0.f,0.f,0.f,0.f,0.f,0.f,0.f,0.f,0.f,0.f,0.f,0.f};
  float m0 = 3.4e38f, m1 = 3.4e38f, m2 = 3.4e38f, m3 = 3.4e38f;

  // Depth-3 min3 tree, same consumption order as R14-R19 (bit-identical).
#define TREE(mj, d) do {                                                     \
    float t0 = fminf(fminf(d[0], d[1]), d[2]);                               \
    float t1 = fminf(fminf(d[3], d[4]), d[5]);                               \
    float t2 = fminf(fminf(d[6], d[7]), d[8]);                               \
    float t3 = fminf(fminf(d[9], d[10]), d[11]);                             \
    float t4 = fminf(fminf(d[12], d[13]), d[14]);                            \
    float u0 = fminf(fminf(t0, t1), d[15]);                                  \
    float u1 = fminf(fminf(t2, t3), t4);                                     \
    mj = fminf(fminf(mj, u0), u1);                                           \
  } while (0)

  bf16x8 bf = *(const bf16x8*)(sB + (0 * 64 + lane) * 8);
  #pragma unroll 1
  for (int rt = 0; rt < 32; ++rt) {
    // Prefetch next row tile: full iteration of slack for the ds_read.
    bf16x8 bfn = bf;
    if (rt < 31) bfn = *(const bf16x8*)(sB + ((rt + 1) * 64 + lane) * 8);
    // 2-deep pipeline: every TREE runs with two MFMAs in flight.
    f32x16 dA = __builtin_amdgcn_mfma_f32_32x32x16_bf16(bf, af0, Z, 0, 0, 0);
    f32x16 dB = __builtin_amdgcn_mfma_f32_32x32x16_bf16(bf, af1, Z, 0, 0, 0);
    TREE(m0, dA);
    dA = __builtin_amdgcn_mfma_f32_32x32x16_bf16(bf, af2, Z, 0, 0, 0);
    TREE(m1, dB);
    dB = __builtin_amdgcn_mfma_f32_32x32x16_bf16(bf, af3, Z, 0, 0, 0);
    TREE(m2, dA);
    TREE(m3, dB);
    bf = bfn;
  }
#undef TREE

  m0 = fminf(m0, __shfl_xor(m0, 32, 64));   // merge complementary row halves
  m1 = fminf(m1, __shfl_xor(m1, 32, 64));
  m2 = fminf(m2, __shfl_xor(m2, 32, 64));
  m3 = fminf(m3, __shfl_xor(m3, 32, 64));
  if (lane < 32) {
    float* dst = partial + (size_t)rq * TOTAL + (size_t)side * NPTS;
    int base = (cg * 16 + w * 4) * 32 + lane;
    dst[base]      = fmaxf(m0, 0.f);
    dst[base + 32] = fmaxf(m1, 0.f);
    dst[base + 64] = fmaxf(m2, 0.f);
    dst[base + 96] = fmaxf(m3, 0.f);
  }
}

// Reduce: min over RSPLIT partials per slot, block-sum, one atomicAdd/block.
// out[0] was zeroed by chamfer_nn (stream-ordered before this kernel).
__global__ __launch_bounds__(TPB) void chamfer_reduce(
    const float* __restrict__ partial, float* __restrict__ out) {
  int t = threadIdx.x;
  int s = blockIdx.x * TPB + t;       // slot 0..65535
  float v = partial[s];
  #pragma unroll
  for (int r = 1; r < RSPLIT; ++r)
    v = fminf(v, partial[(size_t)r * TOTAL + s]);
  #pragma unroll
  for (int off = 32; off > 0; off >>= 1) v += __shfl_down(v, off, 64);
  __shared__ float wsum[4];
  int wave = t >> 6, lane = t & 63;
  if (lane == 0) wsum[wave] = v;
  __syncthreads();
  if (t == 0) {
    float tot = (wsum[0] + wsum[1]) + (wsum[2] + wsum[3]);
    atomicAdd(out, tot * (1.f / (float)(BATCH * NPTS)));
  }
}

extern "C" void kernel_launch(void* const* d_in, const int* in_sizes, int n_in,
                              void* d_out, int out_size, void* d_ws, size_t ws_size,
                              hipStream_t stream) {
  const float* pred = (const float*)d_in[0];
  const float* gt   = (const float*)d_in[1];
  float* out        = (float*)d_out;
  float* partial    = (float*)d_ws;   // RSPLIT x 65536 floats = 2 MB

  chamfer_nn<<<dim3(GRID), dim3(TPB), 0, stream>>>(pred, gt, partial, out);
  chamfer_reduce<<<dim3(TOTAL / TPB), dim3(TPB), 0, stream>>>(partial, out);
}

// Round 11
// 74.903 us; speedup vs baseline: 1.2061x; 1.0408x over previous
//
#include <hip/hip_runtime.h>
#include <hip/hip_bf16.h>

#define BATCH 4
#define NPTS 8192
#define TPB 256
#define RSPLIT 8                    // row-split partial-min slices (no atomics)
#define CGROUPS 16                  // colgroups per side (512 cols each)
#define TOTAL (2 * BATCH * NPTS)    // 65536 output slots
#define GRID (8 * CGROUPS * RSPLIT) // 1024 blocks, 4/CU

typedef short bf16x8 __attribute__((ext_vector_type(8)));
typedef float f32x16 __attribute__((ext_vector_type(16)));

__device__ __forceinline__ unsigned short b16(float f) {   // fp32 -> bf16 RNE (HW cvt)
  __hip_bfloat16 h = __float2bfloat16(f);
  return __builtin_bit_cast(unsigned short, h);
}
__device__ __forceinline__ float b2f(unsigned short h) {
  return __uint_as_float(((unsigned)h) << 16);
}

// K=16 packed rows (R8/R10/R11-verified exact, absmax 0.0):
//  roleA(x): [(-2x)h(3), (-2x)l(3), (-2x)h(3), x2h, x2l, 1,   1,  0,0,0]
//  roleB(y): [yh(3),     yh(3),     yl(3),     1,   1, y2h, y2l, 0,0,0]
// roleA.roleB = squared distance minus (-2x)l.yl (~1e-5 << 9.3e-4 threshold).
__device__ __forceinline__ void pack_halves(uint4* lo, uint4* hi, float cx,
                                            float cy, float cz, bool roleA) {
  float n2 = cx * cx + cy * cy + cz * cz;
  float vx = roleA ? -2.f * cx : cx;
  float vy = roleA ? -2.f * cy : cy;
  float vz = roleA ? -2.f * cz : cz;
  unsigned hx = b16(vx), hy = b16(vy), hz = b16(vz);
  unsigned lx = b16(vx - b2f(hx)), ly = b16(vy - b2f(hy)), lz = b16(vz - b2f(hz));
  unsigned nh = b16(n2), nl = b16(n2 - b2f(nh));
  const unsigned ONE = 0x3F80u;
  if (roleA) {
    *lo = make_uint4(hx | (hy << 16), hz | (lx << 16), ly | (lz << 16), hx | (hy << 16));
    *hi = make_uint4(hz | (nh << 16), nl | (ONE << 16), ONE, 0u);
  } else {
    *lo = make_uint4(hx | (hy << 16), hz | (hx << 16), hy | (hz << 16), lx | (ly << 16));
    *hi = make_uint4(lz | (ONE << 16), ONE | (nh << 16), nl, 0u);
  }
}

// R22 — R15/R19-V0 proven structure (74.5us, absmax 0.0) + VGPR-pinned
// accumulator. R21 LESSON: inline-asm READS of MFMA results are hazard-
// unsafe on hipcc (absmax 4.7e-2) — never consume acc via asm operands.
// Here instead: an EMPTY asm ("" : "+v"(e)x16) pins the 16 acc elements
// into VGPRs (zero instructions, zero semantic change); regalloc then makes
// the MFMA write VGPRs directly (unified file), eliminating the suspected
// 16 v_accvgpr_read/MFMA tax (R19: consumption ~24 ops/MFMA vs nominal 8;
// R16: VALU-issue-saturated at >=4 waves/SIMD). Consumers stay plain fminf
// (hazard-protected, fuse to v_min3). Everything else R15-verified: lane-
// ordered LDS units ((p>>5)*64+(p&31), hi +32; writer/reader lane-stride-1,
// 0 conflicts measured), in-register col pack (lane<32 lo else hi), in-lane
// row-min (C/D: col=lane&31, row=(reg&3)+8*(reg>>2)+4*(lane>>5)),
// shfl_xor(32) merge, coalesced partial stores, separate reduce kernel.
__global__ __launch_bounds__(TPB, 4) void chamfer_nn(
    const float* __restrict__ pred, const float* __restrict__ gt,
    float* __restrict__ partial, float* __restrict__ out) {
  __shared__ __align__(16) unsigned short sB[1024 * 16];   // 32 KB row frags

  int blk = blockIdx.x;
  int rq   = blk & (RSPLIT - 1);         // row slice (1024 rows = 32 tiles)
  int cg   = (blk >> 3) & (CGROUPS - 1); // colgroup (512 cols = 16 tiles)
  int side = blk >> 7;                   // dir*4 + b
  int dir = side >> 2, b = side & 3;

  const float* As = (dir ? gt : pred) + (size_t)b * NPTS * 3;  // cols (outputs)
  const float* Bs = (dir ? pred : gt) + (size_t)b * NPTS * 3;  // rows (min'ed)

  int t = threadIdx.x, w = t >> 6, lane = t & 63;
  if (blk == 0 && t == 0) out[0] = 0.f;   // zero accumulator for reduce pass

  int rowbase = rq * 1024;

  // ---- Stage rows: 4 points/thread into lane-ordered LDS units. ----
  #pragma unroll
  for (int h = 0; h < 4; ++h) {
    int p = h * 256 + t;                 // local row 0..1023
    int gp = rowbase + p;
    uint4 lo, hi;
    pack_halves(&lo, &hi, Bs[gp * 3], Bs[gp * 3 + 1], Bs[gp * 3 + 2], true);
    unsigned short* u0 = sB + ((p >> 5) * 64 + (p & 31)) * 8;
    *(uint4*)u0 = lo;
    *(uint4*)(u0 + 32 * 8) = hi;
  }

  // ---- Col operands in-register: wave w owns col tiles cg*16+w*4+{0..3}.
  bf16x8 af[4];
  #pragma unroll
  for (int j = 0; j < 4; ++j) {
    int gp = (cg * 16 + w * 4 + j) * 32 + (lane & 31);
    uint4 lo, hi;
    pack_halves(&lo, &hi, As[gp * 3], As[gp * 3 + 1], As[gp * 3 + 2], false);
    uint4 sel = (lane < 32) ? lo : hi;
    af[j] = __builtin_bit_cast(bf16x8, sel);
  }

  __syncthreads();   // single barrier: rows staged

  const f32x16 Z = {0.f,0.f,0.f,0.f,0.f,0.f,0.f,0.f,0.f,0.f,0.f,0.f,0.f,0.f,0.f,0.f};
  float m[4] = {3.4e38f, 3.4e38f, 3.4e38f, 3.4e38f};

  #pragma unroll 2
  for (int rt = 0; rt < 32; ++rt) {
    bf16x8 bf = *(const bf16x8*)(sB + (rt * 64 + lane) * 8);
    #pragma unroll
    for (int j = 0; j < 4; ++j) {
      f32x16 d = __builtin_amdgcn_mfma_f32_32x32x16_bf16(bf, af[j], Z, 0, 0, 0);
      // Extract, then pin all 16 into VGPRs with a ZERO-instruction asm.
      float e0 = d[0],  e1 = d[1],  e2 = d[2],  e3 = d[3];
      float e4 = d[4],  e5 = d[5],  e6 = d[6],  e7 = d[7];
      float e8 = d[8],  e9 = d[9],  e10 = d[10], e11 = d[11];
      float e12 = d[12], e13 = d[13], e14 = d[14], e15 = d[15];
      asm("" : "+v"(e0), "+v"(e1), "+v"(e2), "+v"(e3),
               "+v"(e4), "+v"(e5), "+v"(e6), "+v"(e7),
               "+v"(e8), "+v"(e9), "+v"(e10), "+v"(e11),
               "+v"(e12), "+v"(e13), "+v"(e14), "+v"(e15));
      // Proven fminf tree (fuses to v_min3; R14-R19 bit-identical).
      float t0 = fminf(fminf(e0, e1), e2);
      float t1 = fminf(fminf(e3, e4), e5);
      float t2 = fminf(fminf(e6, e7), e8);
      float t3 = fminf(fminf(e9, e10), e11);
      float t4 = fminf(fminf(e12, e13), e14);
      float u0 = fminf(fminf(t0, t1), e15);
      float u1 = fminf(fminf(t2, t3), t4);
      m[j] = fminf(fminf(m[j], u0), u1);
    }
  }

  #pragma unroll
  for (int j = 0; j < 4; ++j)
    m[j] = fminf(m[j], __shfl_xor(m[j], 32, 64));  // merge row halves
  if (lane < 32) {
    float* dst = partial + (size_t)rq * TOTAL + (size_t)side * NPTS;
    #pragma unroll
    for (int j = 0; j < 4; ++j)
      dst[(cg * 16 + w * 4 + j) * 32 + lane] = fmaxf(m[j], 0.f);
  }
}

// Reduce: min over RSPLIT partials per slot, block-sum, one atomicAdd/block.
// out[0] was zeroed by chamfer_nn (stream-ordered before this kernel).
__global__ __launch_bounds__(TPB) void chamfer_reduce(
    const float* __restrict__ partial, float* __restrict__ out) {
  int t = threadIdx.x;
  int s = blockIdx.x * TPB + t;       // slot 0..65535
  float v = partial[s];
  #pragma unroll
  for (int r = 1; r < RSPLIT; ++r)
    v = fminf(v, partial[(size_t)r * TOTAL + s]);
  #pragma unroll
  for (int off = 32; off > 0; off >>= 1) v += __shfl_down(v, off, 64);
  __shared__ float wsum[4];
  int wave = t >> 6, lane = t & 63;
  if (lane == 0) wsum[wave] = v;
  __syncthreads();
  if (t == 0) {
    float tot = (wsum[0] + wsum[1]) + (wsum[2] + wsum[3]);
    atomicAdd(out, tot * (1.f / (float)(BATCH * NPTS)));
  }
}

extern "C" void kernel_launch(void* const* d_in, const int* in_sizes, int n_in,
                              void* d_out, int out_size, void* d_ws, size_t ws_size,
                              hipStream_t stream) {
  const float* pred = (const float*)d_in[0];
  const float* gt   = (const float*)d_in[1];
  float* out        = (float*)d_out;
  float* partial    = (float*)d_ws;   // RSPLIT x 65536 floats = 2 MB

  chamfer_nn<<<dim3(GRID), dim3(TPB), 0, stream>>>(pred, gt, partial, out);
  chamfer_reduce<<<dim3(TOTAL / TPB), dim3(TPB), 0, stream>>>(partial, out);
}